// Round 1
// baseline (421.553 us; speedup 1.0000x reference)
//
#include <hip/hip_runtime.h>

#define NS 115              // contributing samples (S=116, last one unused)
#define WEPS 5e-5f          // per-sample color skip
#define LOG_TSKIP -6.9078f  // chunk1 skip when T < 1e-3
#define NCELLS (128*128*128)
#define PACK_BYTES ((size_t)NCELLS * 64)
#define NRAYS_C 32768
#define WBUF_BYTES ((size_t)NRAYS_C * 128 * 4)
#define NEED_BYTES (PACK_BYTES + WBUF_BYTES)
#define TOTAL_BLOCKS 2048
#define PACK_BLOCKS 1024                      // even blocks
#define PACK_THREADS (PACK_BLOCKS * 256)      // 262144
#define PACK_ITERS ((NCELLS * 4) / PACK_THREADS)   // 32 chunks/thread, exact
#define OP_WAVES (PACK_BLOCKS * 4)            // 4096 op waves
#define RAYS_PER_OPWAVE 8

typedef float f32x4 __attribute__((ext_vector_type(4)));
typedef float f32x2 __attribute__((ext_vector_type(2)));
typedef _Float16 h16x8 __attribute__((ext_vector_type(8)));
typedef _Float16 h16x4 __attribute__((ext_vector_type(4)));

struct SH9 { float a,b,c,d,e,f,g,h,i; };

__device__ __forceinline__ f32x4 load4(const float* p) { f32x4 v; __builtin_memcpy(&v, p, 16); return v; }
__device__ __forceinline__ f32x2 load2(const float* p) { f32x2 v; __builtin_memcpy(&v, p, 8);  return v; }
__device__ __forceinline__ h16x8 load8h(const _Float16* p) { h16x8 v; __builtin_memcpy(&v, p, 16); return v; }
__device__ __forceinline__ h16x4 load4h(const _Float16* p) { h16x4 v; __builtin_memcpy(&v, p, 8);  return v; }
__device__ __forceinline__ f32x4 ntload4(const float* p) {
    return __builtin_nontemporal_load((const f32x4*)p);
}

__device__ __forceinline__ void pos_to_cell(float px, float py, float pz,
                                            int& ibase, float* wxs, float* wys, float* wzs) {
    px = fminf(fmaxf(px, 0.0f), 126.9999f);
    py = fminf(fmaxf(py, 0.0f), 126.9999f);
    pz = fminf(fmaxf(pz, 0.0f), 126.9999f);
    int ix = (int)px, iy = (int)py, iz = (int)pz;
    float wx = px - (float)ix, wy = py - (float)iy, wz = pz - (float)iz;
    ibase = (ix << 14) + (iy << 7) + iz;
    wxs[0] = 1.0f - wx; wxs[1] = wx;
    wys[0] = 1.0f - wy; wys[1] = wy;
    wzs[0] = 1.0f - wz; wzs[1] = wz;
}

// opacity trilerp on the ORIGINAL f32 array; z-adjacent corners via dwordx2.
__device__ __forceinline__ float eval_op(float px, float py, float pz,
                                         const float* __restrict__ opa) {
    int ibase; float wxs[2], wys[2], wzs[2];
    pos_to_cell(px, py, pz, ibase, wxs, wys, wzs);
    float op = 0.0f;
    #pragma unroll
    for (int cx = 0; cx < 2; ++cx)
    #pragma unroll
    for (int cy = 0; cy < 2; ++cy) {
        int idx = ibase + (cx << 14) + (cy << 7);
        f32x2 pr = load2(opa + idx);
        float wxy = wxs[cx] * wys[cy];
        op = fmaf(wxy * wzs[0], pr.x, op);
        op = fmaf(wxy * wzs[1], pr.y, op);
    }
    return fminf(fmaxf(op, 0.0f), 100000.0f);
}

// ---- packed fp16 color: one 64-B aligned cache line per corner ----
__device__ __forceinline__ void eval_color_h(float px, float py, float pz,
                                             const _Float16* __restrict__ pack,
                                             const SH9& sh,
                                             float& cr, float& cg, float& cb) {
    int ibase; float wxs[2], wys[2], wzs[2];
    pos_to_cell(px, py, pz, ibase, wxs, wys, wzs);
    float r = 0.0f, g = 0.0f, b = 0.0f;
    #pragma unroll
    for (int cx = 0; cx < 2; ++cx)
    #pragma unroll
    for (int cy = 0; cy < 2; ++cy)
    #pragma unroll
    for (int cz = 0; cz < 2; ++cz) {
        int idx = ibase + (cx << 14) + (cy << 7) + cz;
        float wc = wxs[cx] * wys[cy] * wzs[cz];
        const _Float16* cp = pack + ((size_t)idx << 5);
        h16x8 v0 = load8h(cp);        // ch 0..7
        h16x8 v1 = load8h(cp + 8);    // ch 8..15
        h16x8 v2 = load8h(cp + 16);   // ch 16..23
        h16x4 v3 = load4h(cp + 24);   // ch 24..26 (+pad)
        float c0 = sh.a*(float)v0[0] + sh.b*(float)v0[1] + sh.c*(float)v0[2] + sh.d*(float)v0[3]
                 + sh.e*(float)v0[4] + sh.f*(float)v0[5] + sh.g*(float)v0[6] + sh.h*(float)v0[7]
                 + sh.i*(float)v1[0];
        float c1 = sh.a*(float)v1[1] + sh.b*(float)v1[2] + sh.c*(float)v1[3] + sh.d*(float)v1[4]
                 + sh.e*(float)v1[5] + sh.f*(float)v1[6] + sh.g*(float)v1[7] + sh.h*(float)v2[0]
                 + sh.i*(float)v2[1];
        float c2 = sh.a*(float)v2[2] + sh.b*(float)v2[3] + sh.c*(float)v2[4] + sh.d*(float)v2[5]
                 + sh.e*(float)v2[6] + sh.f*(float)v2[7] + sh.g*(float)v3[0] + sh.h*(float)v3[1]
                 + sh.i*(float)v3[2];
        r = fmaf(wc, c0, r);
        g = fmaf(wc, c1, g);
        b = fmaf(wc, c2, b);
    }
    cr = fminf(fmaxf(r + 0.5f, 0.0f), 100000.0f);
    cg = fminf(fmaxf(g + 0.5f, 0.0f), 100000.0f);
    cb = fminf(fmaxf(b + 0.5f, 0.0f), 100000.0f);
}

// ---- f32 fallback color (used if ws too small) ----
__device__ __forceinline__ void eval_color_f(float px, float py, float pz,
                                             const float* __restrict__ grid,
                                             const SH9& sh,
                                             float& cr, float& cg, float& cb) {
    int ibase; float wxs[2], wys[2], wzs[2];
    pos_to_cell(px, py, pz, ibase, wxs, wys, wzs);
    float r = 0.0f, g = 0.0f, b = 0.0f;
    #pragma unroll
    for (int cx = 0; cx < 2; ++cx)
    #pragma unroll
    for (int cy = 0; cy < 2; ++cy)
    #pragma unroll
    for (int cz = 0; cz < 2; ++cz) {
        int idx = ibase + (cx << 14) + (cy << 7) + cz;
        float wc = wxs[cx] * wys[cy] * wzs[cz];
        const float* cp = grid + (size_t)idx * 27;
        f32x4 v0 = load4(cp);
        f32x4 v1 = load4(cp + 4);
        f32x4 v2 = load4(cp + 8);
        f32x4 v3 = load4(cp + 12);
        f32x4 v4 = load4(cp + 16);
        f32x4 v5 = load4(cp + 20);
        f32x4 v6 = load4(cp + 23);
        float c0 = sh.a*v0.x + sh.b*v0.y + sh.c*v0.z + sh.d*v0.w
                 + sh.e*v1.x + sh.f*v1.y + sh.g*v1.z + sh.h*v1.w + sh.i*v2.x;
        float c1 = sh.a*v2.y + sh.b*v2.z + sh.c*v2.w + sh.d*v3.x
                 + sh.e*v3.y + sh.f*v3.z + sh.g*v3.w + sh.h*v4.x + sh.i*v4.y;
        float c2 = sh.a*v4.z + sh.b*v4.w + sh.c*v5.x + sh.d*v5.y
                 + sh.e*v5.z + sh.f*v5.w + sh.g*v6.y + sh.h*v6.z + sh.i*v6.w;
        r = fmaf(wc, c0, r);
        g = fmaf(wc, c1, g);
        b = fmaf(wc, c2, b);
    }
    cr = fminf(fmaxf(r + 0.5f, 0.0f), 100000.0f);
    cg = fminf(fmaxf(g + 0.5f, 0.0f), 100000.0f);
    cb = fminf(fmaxf(b + 0.5f, 0.0f), 100000.0f);
}

__device__ __forceinline__ float wave_incl_scan(float v, int lane) {
    #pragma unroll
    for (int off = 1; off < 64; off <<= 1) {
        float n = __shfl_up(v, (unsigned)off, 64);
        if (lane >= off) v += n;
    }
    return v;
}

__device__ __forceinline__ SH9 make_sh(float ddx, float ddy, float ddz) {
    SH9 sh;
    sh.a = 0.28209479177387814f;
    sh.b = -0.4886025119029199f * ddy;
    sh.c =  0.4886025119029199f * ddz;
    sh.d = -0.4886025119029199f * ddx;
    sh.e =  1.0925484305920792f * ddx * ddy;
    sh.f = -1.0925484305920792f * ddy * ddz;
    sh.g =  0.31539156525252005f * (2.0f*ddz*ddz - ddx*ddx - ddy*ddy);
    sh.h = -1.0925484305920792f * ddx * ddz;
    sh.i =  0.5462742152960396f * (ddx*ddx - ddy*ddy);
    return sh;
}

// pack chunk o: output 16-B chunk <-> input floats [(o>>2)*27 + (o&3)*8, +8)
__device__ __forceinline__ void pack_one(const float* __restrict__ grid,
                                         _Float16* __restrict__ pack, int o) {
    int cell = o >> 2;
    int q = o & 3;
    int base = cell * 27;
    int offa = base + ((q == 3) ? 23 : q * 8);
    int offb = (q == 3) ? offa : offa + 4;
    f32x4 a = ntload4(grid + offa);
    f32x4 b = ntload4(grid + offb);
    h16x8 out;
    if (q == 3) {
        out[0] = (_Float16)a.y; out[1] = (_Float16)a.z; out[2] = (_Float16)a.w;
        out[3] = (_Float16)0.f; out[4] = (_Float16)0.f; out[5] = (_Float16)0.f;
        out[6] = (_Float16)0.f; out[7] = (_Float16)0.f;
    } else {
        out[0] = (_Float16)a.x; out[1] = (_Float16)a.y; out[2] = (_Float16)a.z; out[3] = (_Float16)a.w;
        out[4] = (_Float16)b.x; out[5] = (_Float16)b.y; out[6] = (_Float16)b.z; out[7] = (_Float16)b.w;
    }
    __builtin_memcpy(pack + ((size_t)o << 3), &out, 16);
}

struct RayP { float ox,oy,oz,dx,dy,dz,t0,range,delta; };

__device__ __forceinline__ RayP load_ray(const float* __restrict__ x,
                                         const float* __restrict__ d,
                                         const float* __restrict__ tmin,
                                         const float* __restrict__ tmax, int ray) {
    RayP r;
    r.ox = x[3*ray+0]; r.oy = x[3*ray+1]; r.oz = x[3*ray+2];
    r.dx = d[3*ray+0]; r.dy = d[3*ray+1]; r.dz = d[3*ray+2];
    r.t0 = tmin[ray];
    r.range = tmax[ray] - r.t0;
    r.delta = r.range * 0.0078125f;
    return r;
}

// ---- fused prepass, role-split by block parity:
//   even blocks: fp16 pack (HBM-streaming, 32 chunks/thread)
//   odd  blocks: opacity/scan (L2/L3 latency-bound, 8 rays/wave, paired)
// The two phases use disjoint resources (HBM stream vs latency slots+VALU)
// and have no data dependency — running them in concurrent blocks hides the
// op/scan time entirely under the pack's HBM window.
__global__ __launch_bounds__(256) void pack_op_kernel(
    const float* __restrict__ grid, _Float16* __restrict__ pack,
    const float* __restrict__ x, const float* __restrict__ d,
    const float* __restrict__ tmin, const float* __restrict__ tmax,
    const float* __restrict__ opa, float* __restrict__ wbuf, int nrays)
{
    const int t = threadIdx.x;
    const int role_id = blockIdx.x >> 1;   // 0..1023 within role

    if ((blockIdx.x & 1) == 0) {
        // ---- pack role: 32 chunks/thread, pipelined 8 deep (16 loads in flight)
        const int tid = role_id * 256 + t;
        #pragma unroll 1
        for (int i = 0; i < PACK_ITERS; i += 8) {
            #pragma unroll
            for (int j = 0; j < 8; ++j)
                pack_one(grid, pack, tid + (i + j) * PACK_THREADS);
        }
        return;
    }

    // ---- op role: opacity + transmittance scan, 8 rays/wave, 2-way interleave
    const int otid = role_id * 256 + t;
    const int wave = otid >> 6;            // 0..4095
    const int lane = t & 63;
    const int rbase = wave * RAYS_PER_OPWAVE;
    const float fl = (float)lane;

    #pragma unroll 1
    for (int p = 0; p < RAYS_PER_OPWAVE / 2; ++p) {
        int rayA = __builtin_amdgcn_readfirstlane(rbase + 2 * p);
        if (rayA >= nrays) break;
        int rayBr = rayA + 1;
        bool hasB = rayBr < nrays;
        int rayB = hasB ? rayBr : rayA;

        RayP A = load_ray(x, d, tmin, tmax, rayA);
        RayP B = load_ray(x, d, tmin, tmax, rayB);

        // chunk 0: samples 0..63 — both rays' gathers issued together
        float ttA = A.range * (0.05f + fl * 0.0078125f) + A.t0;
        float ttB = B.range * (0.05f + fl * 0.0078125f) + B.t0;
        float pxA = A.ox + ttA*A.dx, pyA = A.oy + ttA*A.dy, pzA = A.oz + ttA*A.dz;
        float pxB = B.ox + ttB*B.dx, pyB = B.oy + ttB*B.dy, pzB = B.oz + ttB*B.dz;
        float opA = eval_op(pxA, pyA, pzA, opa);
        float opB = eval_op(pxB, pyB, pzB, opa);
        float dtsA = -A.delta * opA;
        float dtsB = -B.delta * opB;
        float inclA = wave_incl_scan(dtsA, lane);
        float inclB = wave_incl_scan(dtsB, lane);
        float cumA = inclA - dtsA;
        float cumB = inclB - dtsB;
        float totalA = __shfl(inclA, 63, 64);
        float totalB = __shfl(inclB, 63, 64);
        wbuf[rayA * 128 + lane] = __expf(cumA) * (1.0f - __expf(dtsA));
        if (hasB) wbuf[rayB * 128 + lane] = __expf(cumB) * (1.0f - __expf(dtsB));

        // chunk 1: samples 64..114 (0 when transmittance dead or s>=NS)
        float w1A = 0.0f;
        if (totalA > LOG_TSKIP) {
            int s1 = 64 + lane;
            float dts1 = 0.0f;
            if (s1 < NS) {
                float t1s = A.range * (0.05f + (float)s1 * 0.0078125f) + A.t0;
                float qx = A.ox + t1s*A.dx, qy = A.oy + t1s*A.dy, qz = A.oz + t1s*A.dz;
                dts1 = -A.delta * eval_op(qx, qy, qz, opa);
            }
            float incl1 = wave_incl_scan(dts1, lane);
            float cum1 = totalA + incl1 - dts1;
            w1A = __expf(cum1) * (1.0f - __expf(dts1));   // ==0 for s1>=NS
        }
        wbuf[rayA * 128 + 64 + lane] = w1A;

        if (hasB) {
            float w1B = 0.0f;
            if (totalB > LOG_TSKIP) {
                int s1 = 64 + lane;
                float dts1 = 0.0f;
                if (s1 < NS) {
                    float t1s = B.range * (0.05f + (float)s1 * 0.0078125f) + B.t0;
                    float qx = B.ox + t1s*B.dx, qy = B.oy + t1s*B.dy, qz = B.oz + t1s*B.dz;
                    dts1 = -B.delta * eval_op(qx, qy, qz, opa);
                }
                float incl1 = wave_incl_scan(dts1, lane);
                float cum1 = totalB + incl1 - dts1;
                w1B = __expf(cum1) * (1.0f - __expf(dts1));
            }
            wbuf[rayB * 128 + 64 + lane] = w1B;
        }
    }
}

// ---- color kernel: wave per ray, lane = sample; reads w, gathers packed
// fp16 cells only where w > WEPS ----
__global__ __launch_bounds__(256) void color_kernel(
    const float* __restrict__ x, const float* __restrict__ d,
    const float* __restrict__ tmin, const float* __restrict__ tmax,
    const _Float16* __restrict__ pack, const float* __restrict__ wbuf,
    float* __restrict__ out, int nrays)
{
    int gtid = blockIdx.x * blockDim.x + threadIdx.x;
    int ray = __builtin_amdgcn_readfirstlane(gtid >> 6);
    int lane = threadIdx.x & 63;
    if (ray >= nrays) return;

    float ox = x[3*ray+0], oy = x[3*ray+1], oz = x[3*ray+2];
    float ddx = d[3*ray+0], ddy = d[3*ray+1], ddz = d[3*ray+2];
    float t0 = tmin[ray], t1 = tmax[ray];
    float range = t1 - t0;
    SH9 sh = make_sh(ddx, ddy, ddz);

    float w0 = wbuf[ray * 128 + lane];
    float w1 = wbuf[ray * 128 + 64 + lane];

    float accR = 0.0f, accG = 0.0f, accB = 0.0f;
    if (w0 > WEPS) {
        float tt = range * (0.05f + (float)lane * 0.0078125f) + t0;
        float px = ox + tt*ddx, py = oy + tt*ddy, pz = oz + tt*ddz;
        float cr, cg, cb;
        eval_color_h(px, py, pz, pack, sh, cr, cg, cb);
        accR = w0 * cr; accG = w0 * cg; accB = w0 * cb;
    }
    if (w1 > WEPS) {   // implies 64+lane < NS and chunk1 taken
        float t1s = range * (0.05f + (float)(64 + lane) * 0.0078125f) + t0;
        float px = ox + t1s*ddx, py = oy + t1s*ddy, pz = oz + t1s*ddz;
        float cr, cg, cb;
        eval_color_h(px, py, pz, pack, sh, cr, cg, cb);
        accR = fmaf(w1, cr, accR);
        accG = fmaf(w1, cg, accG);
        accB = fmaf(w1, cb, accB);
    }

    #pragma unroll
    for (int off = 32; off > 0; off >>= 1) {
        accR += __shfl_xor(accR, off, 64);
        accG += __shfl_xor(accG, off, 64);
        accB += __shfl_xor(accB, off, 64);
    }
    if (lane == 0) {
        out[3*ray+0] = accR;
        out[3*ray+1] = accG;
        out[3*ray+2] = accB;
    }
}

// ---- fallback: fully-fused f32 path (ws too small) ----
__global__ __launch_bounds__(256) void rf_fallback(
    const float* __restrict__ x, const float* __restrict__ d,
    const float* __restrict__ tmin, const float* __restrict__ tmax,
    const float* __restrict__ grid, const float* __restrict__ opa,
    float* __restrict__ out, int nrays)
{
    int gtid = blockIdx.x * blockDim.x + threadIdx.x;
    int ray = __builtin_amdgcn_readfirstlane(gtid >> 6);
    int lane = threadIdx.x & 63;
    if (ray >= nrays) return;

    float ox = x[3*ray+0], oy = x[3*ray+1], oz = x[3*ray+2];
    float ddx = d[3*ray+0], ddy = d[3*ray+1], ddz = d[3*ray+2];
    float t0 = tmin[ray], t1 = tmax[ray];
    float range = t1 - t0;
    float delta = range * 0.0078125f;
    SH9 sh = make_sh(ddx, ddy, ddz);

    float accR = 0.0f, accG = 0.0f, accB = 0.0f;
    {
        float tt = range * (0.05f + (float)lane * 0.0078125f) + t0;
        float px = ox + tt*ddx, py = oy + tt*ddy, pz = oz + tt*ddz;
        float opv = eval_op(px, py, pz, opa);
        float dts = -delta * opv;
        float incl = wave_incl_scan(dts, lane);
        float cum = incl - dts;
        float total0 = __shfl(incl, 63, 64);
        float w = __expf(cum) * (1.0f - __expf(dts));
        if (w > WEPS) {
            float cr, cg, cb;
            eval_color_f(px, py, pz, grid, sh, cr, cg, cb);
            accR = w * cr; accG = w * cg; accB = w * cb;
        }
        if (total0 > LOG_TSKIP) {
            int s1 = 64 + lane;
            float dts1 = 0.0f;
            float px1 = 0.f, py1 = 0.f, pz1 = 0.f;
            if (s1 < NS) {
                float t1s = range * (0.05f + (float)s1 * 0.0078125f) + t0;
                px1 = ox + t1s*ddx; py1 = oy + t1s*ddy; pz1 = oz + t1s*ddz;
                dts1 = -delta * eval_op(px1, py1, pz1, opa);
            }
            float incl1 = wave_incl_scan(dts1, lane);
            float cum1 = total0 + incl1 - dts1;
            float w1 = __expf(cum1) * (1.0f - __expf(dts1));
            if (w1 > WEPS) {
                float cr, cg, cb;
                eval_color_f(px1, py1, pz1, grid, sh, cr, cg, cb);
                accR = fmaf(w1, cr, accR);
                accG = fmaf(w1, cg, accG);
                accB = fmaf(w1, cb, accB);
            }
        }
    }
    #pragma unroll
    for (int off = 32; off > 0; off >>= 1) {
        accR += __shfl_xor(accR, off, 64);
        accG += __shfl_xor(accG, off, 64);
        accB += __shfl_xor(accB, off, 64);
    }
    if (lane == 0) {
        out[3*ray+0] = accR;
        out[3*ray+1] = accG;
        out[3*ray+2] = accB;
    }
}

extern "C" void kernel_launch(void* const* d_in, const int* in_sizes, int n_in,
                              void* d_out, int out_size, void* d_ws, size_t ws_size,
                              hipStream_t stream) {
    const float* x    = (const float*)d_in[0];
    const float* d    = (const float*)d_in[1];
    const float* tmin = (const float*)d_in[2];
    const float* tmax = (const float*)d_in[3];
    const float* grid = (const float*)d_in[4];
    const float* opa  = (const float*)d_in[5];
    float* out = (float*)d_out;

    int nrays = in_sizes[0] / 3;                 // 32768
    int blocks = (nrays * 64 + 255) / 256;       // 8192

    if (ws_size >= NEED_BYTES && nrays <= NRAYS_C) {
        _Float16* pack = (_Float16*)d_ws;
        float* wbuf = (float*)((char*)d_ws + PACK_BYTES);
        pack_op_kernel<<<TOTAL_BLOCKS, 256, 0, stream>>>(grid, pack, x, d, tmin, tmax, opa, wbuf, nrays);
        color_kernel<<<blocks, 256, 0, stream>>>(x, d, tmin, tmax, pack, wbuf, out, nrays);
    } else {
        rf_fallback<<<blocks, 256, 0, stream>>>(x, d, tmin, tmax, grid, opa, out, nrays);
    }
}

// Round 2
// 401.584 us; speedup vs baseline: 1.0497x; 1.0497x over previous
//
#include <hip/hip_runtime.h>

#define NS 115              // contributing samples (S=116, last one unused)
#define WEPS 5e-5f          // per-sample color skip
#define LOG_TSKIP -6.9078f  // chunk1 skip when T < 1e-3
#define NCELLS (128*128*128)
#define PACK_BYTES ((size_t)NCELLS * 64)
#define NRAYS_C 32768
#define WBUF_BYTES ((size_t)NRAYS_C * 128 * 4)
#define NEED_BYTES (PACK_BYTES + WBUF_BYTES)
#define PACK_BLOCKS 2048
#define PACK_THREADS (PACK_BLOCKS * 256)
#define PACK_ITERS ((NCELLS * 4) / PACK_THREADS)   // 16 chunks/thread, exact

typedef float f32x4 __attribute__((ext_vector_type(4)));
typedef float f32x2 __attribute__((ext_vector_type(2)));
typedef _Float16 h16x8 __attribute__((ext_vector_type(8)));
typedef _Float16 h16x4 __attribute__((ext_vector_type(4)));

struct SH9 { float a,b,c,d,e,f,g,h,i; };

__device__ __forceinline__ f32x4 load4(const float* p) { f32x4 v; __builtin_memcpy(&v, p, 16); return v; }
__device__ __forceinline__ f32x2 load2(const float* p) { f32x2 v; __builtin_memcpy(&v, p, 8);  return v; }
__device__ __forceinline__ h16x8 load8h(const _Float16* p) { h16x8 v; __builtin_memcpy(&v, p, 16); return v; }
__device__ __forceinline__ h16x4 load4h(const _Float16* p) { h16x4 v; __builtin_memcpy(&v, p, 8);  return v; }
__device__ __forceinline__ f32x4 ntload4(const float* p) {
    return __builtin_nontemporal_load((const f32x4*)p);
}

__device__ __forceinline__ void pos_to_cell(float px, float py, float pz,
                                            int& ibase, float* wxs, float* wys, float* wzs) {
    px = fminf(fmaxf(px, 0.0f), 126.9999f);
    py = fminf(fmaxf(py, 0.0f), 126.9999f);
    pz = fminf(fmaxf(pz, 0.0f), 126.9999f);
    int ix = (int)px, iy = (int)py, iz = (int)pz;
    float wx = px - (float)ix, wy = py - (float)iy, wz = pz - (float)iz;
    ibase = (ix << 14) + (iy << 7) + iz;
    wxs[0] = 1.0f - wx; wxs[1] = wx;
    wys[0] = 1.0f - wy; wys[1] = wy;
    wzs[0] = 1.0f - wz; wzs[1] = wz;
}

// opacity trilerp on the ORIGINAL f32 array; z-adjacent corners via dwordx2.
__device__ __forceinline__ float eval_op(float px, float py, float pz,
                                         const float* __restrict__ opa) {
    int ibase; float wxs[2], wys[2], wzs[2];
    pos_to_cell(px, py, pz, ibase, wxs, wys, wzs);
    float op = 0.0f;
    #pragma unroll
    for (int cx = 0; cx < 2; ++cx)
    #pragma unroll
    for (int cy = 0; cy < 2; ++cy) {
        int idx = ibase + (cx << 14) + (cy << 7);
        f32x2 pr = load2(opa + idx);
        float wxy = wxs[cx] * wys[cy];
        op = fmaf(wxy * wzs[0], pr.x, op);
        op = fmaf(wxy * wzs[1], pr.y, op);
    }
    return fminf(fmaxf(op, 0.0f), 100000.0f);
}

// ---- f32 fallback color (used if ws too small) ----
__device__ __forceinline__ void eval_color_f(float px, float py, float pz,
                                             const float* __restrict__ grid,
                                             const SH9& sh,
                                             float& cr, float& cg, float& cb) {
    int ibase; float wxs[2], wys[2], wzs[2];
    pos_to_cell(px, py, pz, ibase, wxs, wys, wzs);
    float r = 0.0f, g = 0.0f, b = 0.0f;
    #pragma unroll
    for (int cx = 0; cx < 2; ++cx)
    #pragma unroll
    for (int cy = 0; cy < 2; ++cy)
    #pragma unroll
    for (int cz = 0; cz < 2; ++cz) {
        int idx = ibase + (cx << 14) + (cy << 7) + cz;
        float wc = wxs[cx] * wys[cy] * wzs[cz];
        const float* cp = grid + (size_t)idx * 27;
        f32x4 v0 = load4(cp);
        f32x4 v1 = load4(cp + 4);
        f32x4 v2 = load4(cp + 8);
        f32x4 v3 = load4(cp + 12);
        f32x4 v4 = load4(cp + 16);
        f32x4 v5 = load4(cp + 20);
        f32x4 v6 = load4(cp + 23);
        float c0 = sh.a*v0.x + sh.b*v0.y + sh.c*v0.z + sh.d*v0.w
                 + sh.e*v1.x + sh.f*v1.y + sh.g*v1.z + sh.h*v1.w + sh.i*v2.x;
        float c1 = sh.a*v2.y + sh.b*v2.z + sh.c*v2.w + sh.d*v3.x
                 + sh.e*v3.y + sh.f*v3.z + sh.g*v3.w + sh.h*v4.x + sh.i*v4.y;
        float c2 = sh.a*v4.z + sh.b*v4.w + sh.c*v5.x + sh.d*v5.y
                 + sh.e*v5.z + sh.f*v5.w + sh.g*v6.y + sh.h*v6.z + sh.i*v6.w;
        r = fmaf(wc, c0, r);
        g = fmaf(wc, c1, g);
        b = fmaf(wc, c2, b);
    }
    cr = fminf(fmaxf(r + 0.5f, 0.0f), 100000.0f);
    cg = fminf(fmaxf(g + 0.5f, 0.0f), 100000.0f);
    cb = fminf(fmaxf(b + 0.5f, 0.0f), 100000.0f);
}

__device__ __forceinline__ float wave_incl_scan(float v, int lane) {
    #pragma unroll
    for (int off = 1; off < 64; off <<= 1) {
        float n = __shfl_up(v, (unsigned)off, 64);
        if (lane >= off) v += n;
    }
    return v;
}

__device__ __forceinline__ SH9 make_sh(float ddx, float ddy, float ddz) {
    SH9 sh;
    sh.a = 0.28209479177387814f;
    sh.b = -0.4886025119029199f * ddy;
    sh.c =  0.4886025119029199f * ddz;
    sh.d = -0.4886025119029199f * ddx;
    sh.e =  1.0925484305920792f * ddx * ddy;
    sh.f = -1.0925484305920792f * ddy * ddz;
    sh.g =  0.31539156525252005f * (2.0f*ddz*ddz - ddx*ddx - ddy*ddy);
    sh.h = -1.0925484305920792f * ddx * ddz;
    sh.i =  0.5462742152960396f * (ddx*ddx - ddy*ddy);
    return sh;
}

// pack chunk o: output 16-B chunk <-> input floats [(o>>2)*27 + (o&3)*8, +8)
__device__ __forceinline__ void pack_one(const float* __restrict__ grid,
                                         _Float16* __restrict__ pack, int o) {
    int cell = o >> 2;
    int q = o & 3;
    int base = cell * 27;
    int offa = base + ((q == 3) ? 23 : q * 8);
    int offb = (q == 3) ? offa : offa + 4;
    f32x4 a = ntload4(grid + offa);
    f32x4 b = ntload4(grid + offb);
    h16x8 out;
    if (q == 3) {
        out[0] = (_Float16)a.y; out[1] = (_Float16)a.z; out[2] = (_Float16)a.w;
        out[3] = (_Float16)0.f; out[4] = (_Float16)0.f; out[5] = (_Float16)0.f;
        out[6] = (_Float16)0.f; out[7] = (_Float16)0.f;
    } else {
        out[0] = (_Float16)a.x; out[1] = (_Float16)a.y; out[2] = (_Float16)a.z; out[3] = (_Float16)a.w;
        out[4] = (_Float16)b.x; out[5] = (_Float16)b.y; out[6] = (_Float16)b.z; out[7] = (_Float16)b.w;
    }
    __builtin_memcpy(pack + ((size_t)o << 3), &out, 16);
}

// ---- fused prepass (round-0 serial structure): fp16 pack, then op/scan ----
__global__ __launch_bounds__(256) void pack_op_kernel(
    const float* __restrict__ grid, _Float16* __restrict__ pack,
    const float* __restrict__ x, const float* __restrict__ d,
    const float* __restrict__ tmin, const float* __restrict__ tmax,
    const float* __restrict__ opa, float* __restrict__ wbuf, int nrays)
{
    const int t = threadIdx.x;
    const int tid = blockIdx.x * 256 + t;

    // ---- pack phase: 16 chunks/thread, 8 deep (16 loads in flight) ----
    #pragma unroll 1
    for (int i = 0; i < PACK_ITERS; i += 8) {
        #pragma unroll
        for (int j = 0; j < 8; ++j)
            pack_one(grid, pack, tid + (i + j) * PACK_THREADS);
    }

    // ---- opacity + transmittance scan: 4 rays per wave ----
    const int wave = tid >> 6;           // 0..8191
    const int lane = t & 63;
    #pragma unroll 1
    for (int r = 0; r < 4; ++r) {
        int ray = __builtin_amdgcn_readfirstlane(wave * 4 + r);
        if (ray >= nrays) break;
        float ox = x[3*ray+0], oy = x[3*ray+1], oz = x[3*ray+2];
        float ddx = d[3*ray+0], ddy = d[3*ray+1], ddz = d[3*ray+2];
        float t0 = tmin[ray], t1 = tmax[ray];
        float range = t1 - t0;
        float delta = range * 0.0078125f;

        // chunk 0: samples 0..63
        float tt = range * (0.05f + (float)lane * 0.0078125f) + t0;
        float px = ox + tt*ddx, py = oy + tt*ddy, pz = oz + tt*ddz;
        float opv = eval_op(px, py, pz, opa);
        float dts = -delta * opv;
        float incl = wave_incl_scan(dts, lane);
        float cum = incl - dts;
        float total0 = __shfl(incl, 63, 64);
        float w = __expf(cum) * (1.0f - __expf(dts));
        wbuf[ray * 128 + lane] = w;

        // chunk 1: samples 64..114 (0 when transmittance dead or s>=NS)
        float w1 = 0.0f;
        if (total0 > LOG_TSKIP) {
            int s1 = 64 + lane;
            float dts1 = 0.0f;
            if (s1 < NS) {
                float t1s = range * (0.05f + (float)s1 * 0.0078125f) + t0;
                float qx = ox + t1s*ddx, qy = oy + t1s*ddy, qz = oz + t1s*ddz;
                dts1 = -delta * eval_op(qx, qy, qz, opa);
            }
            float incl1 = wave_incl_scan(dts1, lane);
            float cum1 = total0 + incl1 - dts1;
            w1 = __expf(cum1) * (1.0f - __expf(dts1));   // ==0 for s1>=NS
        }
        wbuf[ray * 128 + 64 + lane] = w1;
    }
}

// ---- color kernel: wave per ray, QUAD-cooperative gather.
// Each sample is handled by a 4-lane quad; lane (sub=lane&3) loads one 16-B
// quarter of each corner's 64-B cell line -> the coalescer merges the quad
// into ONE 64-B transaction per corner (8 txns/sample vs 32 before).
// Per-lane channels [8*sub, 8*sub+8) span at most 2 colors -> two masked
// 8-dots (d0,d1), routed to (r,g,b) per sub, then a 2-step quad reduce.
__global__ __launch_bounds__(256) void color_kernel(
    const float* __restrict__ x, const float* __restrict__ d,
    const float* __restrict__ tmin, const float* __restrict__ tmax,
    const _Float16* __restrict__ pack, const float* __restrict__ wbuf,
    float* __restrict__ out, int nrays)
{
    int gtid = blockIdx.x * blockDim.x + threadIdx.x;
    int ray = __builtin_amdgcn_readfirstlane(gtid >> 6);
    int lane = threadIdx.x & 63;
    if (ray >= nrays) return;
    int qd  = lane >> 2;    // quad id: sample-within-pass
    int sub = lane & 3;     // 16-B quarter within cell line

    float ox = x[3*ray+0], oy = x[3*ray+1], oz = x[3*ray+2];
    float ddx = d[3*ray+0], ddy = d[3*ray+1], ddz = d[3*ray+2];
    float t0 = tmin[ray];
    float range = tmax[ray] - t0;
    SH9 sh = make_sh(ddx, ddy, ddz);

    // per-lane dual masked SH vectors:
    // sub0: ch0-7  = R sh0-7          -> s0={a..h}, s1=0
    // sub1: ch8-15 = R sh8, G sh0-6   -> s0={i,0..}, s1={0,a..g}
    // sub2: ch16-23= G sh7-8, B sh0-5 -> s0={h,i,0..}, s1={0,0,a..f}
    // sub3: ch24-26= B sh6-8 (+pad0)  -> s0={g,h,i,0..}, s1=0
    float s00,s01,s02,s03,s04,s05,s06,s07;
    float s10,s11,s12,s13,s14,s15,s16,s17;
    if (sub == 0) {
        s00=sh.a;s01=sh.b;s02=sh.c;s03=sh.d;s04=sh.e;s05=sh.f;s06=sh.g;s07=sh.h;
        s10=0.f;s11=0.f;s12=0.f;s13=0.f;s14=0.f;s15=0.f;s16=0.f;s17=0.f;
    } else if (sub == 1) {
        s00=sh.i;s01=0.f;s02=0.f;s03=0.f;s04=0.f;s05=0.f;s06=0.f;s07=0.f;
        s10=0.f;s11=sh.a;s12=sh.b;s13=sh.c;s14=sh.d;s15=sh.e;s16=sh.f;s17=sh.g;
    } else if (sub == 2) {
        s00=sh.h;s01=sh.i;s02=0.f;s03=0.f;s04=0.f;s05=0.f;s06=0.f;s07=0.f;
        s10=0.f;s11=0.f;s12=sh.a;s13=sh.b;s14=sh.c;s15=sh.d;s16=sh.e;s17=sh.f;
    } else {
        s00=sh.g;s01=sh.h;s02=sh.i;s03=0.f;s04=0.f;s05=0.f;s06=0.f;s07=0.f;
        s10=0.f;s11=0.f;s12=0.f;s13=0.f;s14=0.f;s15=0.f;s16=0.f;s17=0.f;
    }

    float w0 = wbuf[ray * 128 + lane];
    float w1 = wbuf[ray * 128 + 64 + lane];
    unsigned long long b0 = __ballot(w0 > WEPS);
    unsigned long long b1 = __ballot(w1 > WEPS);

    float accR = 0.0f, accG = 0.0f, accB = 0.0f;

    #pragma unroll 1
    for (int p = 0; p < 8; ++p) {
        unsigned long long bsel = (p < 4) ? b0 : b1;
        int shl = (p & 3) << 4;
        if (((bsel >> shl) & 0xFFFFull) == 0) continue;   // whole pass dead
        int s = (p << 4) + qd;                            // sample index
        float ws = __shfl((p < 4) ? w0 : w1, s & 63, 64); // quad-uniform
        if (ws > WEPS) {
            float tt = range * (0.05f + (float)s * 0.0078125f) + t0;
            float px = ox + tt*ddx, py = oy + tt*ddy, pz = oz + tt*ddz;
            int ibase; float wxs[2], wys[2], wzs[2];
            pos_to_cell(px, py, pz, ibase, wxs, wys, wzs);
            float d0a = 0.0f, d1a = 0.0f;   // wc-weighted dual dots over corners
            #pragma unroll
            for (int cx = 0; cx < 2; ++cx)
            #pragma unroll
            for (int cy = 0; cy < 2; ++cy)
            #pragma unroll
            for (int cz = 0; cz < 2; ++cz) {
                int idx = ibase + (cx << 14) + (cy << 7) + cz;
                float wc = wxs[cx] * wys[cy] * wzs[cz];
                const _Float16* cp = pack + ((size_t)idx << 5) + (sub << 3);
                h16x8 v = load8h(cp);
                float f0=(float)v[0], f1=(float)v[1], f2=(float)v[2], f3=(float)v[3];
                float f4=(float)v[4], f5=(float)v[5], f6=(float)v[6], f7=(float)v[7];
                float e0 = s00*f0 + s01*f1 + s02*f2 + s03*f3
                         + s04*f4 + s05*f5 + s06*f6 + s07*f7;
                float e1 = s10*f0 + s11*f1 + s12*f2 + s13*f3
                         + s14*f4 + s15*f5 + s16*f6 + s17*f7;
                d0a = fmaf(wc, e0, d0a);
                d1a = fmaf(wc, e1, d1a);
            }
            // route dual dots to colors (per-sub mapping)
            float rp = (sub < 2)  ? d0a : 0.0f;
            float gp = (sub == 1) ? d1a : ((sub == 2) ? d0a : 0.0f);
            float bp = (sub == 2) ? d1a : ((sub == 3) ? d0a : 0.0f);
            // quad reduce (all 4 quad-lanes active together)
            rp += __shfl_xor(rp, 1, 64); rp += __shfl_xor(rp, 2, 64);
            gp += __shfl_xor(gp, 1, 64); gp += __shfl_xor(gp, 2, 64);
            bp += __shfl_xor(bp, 1, 64); bp += __shfl_xor(bp, 2, 64);
            float cr = fminf(fmaxf(rp + 0.5f, 0.0f), 100000.0f);
            float cg = fminf(fmaxf(gp + 0.5f, 0.0f), 100000.0f);
            float cb = fminf(fmaxf(bp + 0.5f, 0.0f), 100000.0f);
            accR = fmaf(ws, cr, accR);
            accG = fmaf(ws, cg, accG);
            accB = fmaf(ws, cb, accB);
        }
    }

    // quad lanes hold identical acc -> reduce across quads only
    #pragma unroll
    for (int off = 4; off < 64; off <<= 1) {
        accR += __shfl_xor(accR, off, 64);
        accG += __shfl_xor(accG, off, 64);
        accB += __shfl_xor(accB, off, 64);
    }
    if (lane == 0) {
        out[3*ray+0] = accR;
        out[3*ray+1] = accG;
        out[3*ray+2] = accB;
    }
}

// ---- fallback: fully-fused f32 path (ws too small) ----
__global__ __launch_bounds__(256) void rf_fallback(
    const float* __restrict__ x, const float* __restrict__ d,
    const float* __restrict__ tmin, const float* __restrict__ tmax,
    const float* __restrict__ grid, const float* __restrict__ opa,
    float* __restrict__ out, int nrays)
{
    int gtid = blockIdx.x * blockDim.x + threadIdx.x;
    int ray = __builtin_amdgcn_readfirstlane(gtid >> 6);
    int lane = threadIdx.x & 63;
    if (ray >= nrays) return;

    float ox = x[3*ray+0], oy = x[3*ray+1], oz = x[3*ray+2];
    float ddx = d[3*ray+0], ddy = d[3*ray+1], ddz = d[3*ray+2];
    float t0 = tmin[ray], t1 = tmax[ray];
    float range = t1 - t0;
    float delta = range * 0.0078125f;
    SH9 sh = make_sh(ddx, ddy, ddz);

    float accR = 0.0f, accG = 0.0f, accB = 0.0f;
    {
        float tt = range * (0.05f + (float)lane * 0.0078125f) + t0;
        float px = ox + tt*ddx, py = oy + tt*ddy, pz = oz + tt*ddz;
        float opv = eval_op(px, py, pz, opa);
        float dts = -delta * opv;
        float incl = wave_incl_scan(dts, lane);
        float cum = incl - dts;
        float total0 = __shfl(incl, 63, 64);
        float w = __expf(cum) * (1.0f - __expf(dts));
        if (w > WEPS) {
            float cr, cg, cb;
            eval_color_f(px, py, pz, grid, sh, cr, cg, cb);
            accR = w * cr; accG = w * cg; accB = w * cb;
        }
        if (total0 > LOG_TSKIP) {
            int s1 = 64 + lane;
            float dts1 = 0.0f;
            float px1 = 0.f, py1 = 0.f, pz1 = 0.f;
            if (s1 < NS) {
                float t1s = range * (0.05f + (float)s1 * 0.0078125f) + t0;
                px1 = ox + t1s*ddx; py1 = oy + t1s*ddy; pz1 = oz + t1s*ddz;
                dts1 = -delta * eval_op(px1, py1, pz1, opa);
            }
            float incl1 = wave_incl_scan(dts1, lane);
            float cum1 = total0 + incl1 - dts1;
            float w1 = __expf(cum1) * (1.0f - __expf(dts1));
            if (w1 > WEPS) {
                float cr, cg, cb;
                eval_color_f(px1, py1, pz1, grid, sh, cr, cg, cb);
                accR = fmaf(w1, cr, accR);
                accG = fmaf(w1, cg, accG);
                accB = fmaf(w1, cb, accB);
            }
        }
    }
    #pragma unroll
    for (int off = 32; off > 0; off >>= 1) {
        accR += __shfl_xor(accR, off, 64);
        accG += __shfl_xor(accG, off, 64);
        accB += __shfl_xor(accB, off, 64);
    }
    if (lane == 0) {
        out[3*ray+0] = accR;
        out[3*ray+1] = accG;
        out[3*ray+2] = accB;
    }
}

extern "C" void kernel_launch(void* const* d_in, const int* in_sizes, int n_in,
                              void* d_out, int out_size, void* d_ws, size_t ws_size,
                              hipStream_t stream) {
    const float* x    = (const float*)d_in[0];
    const float* d    = (const float*)d_in[1];
    const float* tmin = (const float*)d_in[2];
    const float* tmax = (const float*)d_in[3];
    const float* grid = (const float*)d_in[4];
    const float* opa  = (const float*)d_in[5];
    float* out = (float*)d_out;

    int nrays = in_sizes[0] / 3;                 // 32768
    int blocks = (nrays * 64 + 255) / 256;       // 8192

    if (ws_size >= NEED_BYTES && nrays <= NRAYS_C) {
        _Float16* pack = (_Float16*)d_ws;
        float* wbuf = (float*)((char*)d_ws + PACK_BYTES);
        pack_op_kernel<<<PACK_BLOCKS, 256, 0, stream>>>(grid, pack, x, d, tmin, tmax, opa, wbuf, nrays);
        color_kernel<<<blocks, 256, 0, stream>>>(x, d, tmin, tmax, pack, wbuf, out, nrays);
    } else {
        rf_fallback<<<blocks, 256, 0, stream>>>(x, d, tmin, tmax, grid, opa, out, nrays);
    }
}

// Round 3
// 391.726 us; speedup vs baseline: 1.0761x; 1.0252x over previous
//
#include <hip/hip_runtime.h>

#define NS 115              // contributing samples (S=116, last one unused)
#define WEPS 5e-5f          // per-sample color skip
#define LOG_TSKIP -6.9078f  // chunk1 skip when T < 1e-3
#define NCELLS (128*128*128)
#define PACK_BYTES ((size_t)NCELLS * 64)
#define NEED_BYTES PACK_BYTES
#define PACK_BLOCKS 2048
#define PACK_THREADS (PACK_BLOCKS * 256)
#define PACK_ITERS ((NCELLS * 4) / PACK_THREADS)   // 16 chunks/thread, exact

typedef float f32x4 __attribute__((ext_vector_type(4)));
typedef float f32x2 __attribute__((ext_vector_type(2)));
typedef _Float16 h16x8 __attribute__((ext_vector_type(8)));
typedef _Float16 h16x4 __attribute__((ext_vector_type(4)));

struct SH9 { float a,b,c,d,e,f,g,h,i; };

__device__ __forceinline__ f32x4 load4(const float* p) { f32x4 v; __builtin_memcpy(&v, p, 16); return v; }
__device__ __forceinline__ f32x2 load2(const float* p) { f32x2 v; __builtin_memcpy(&v, p, 8);  return v; }
__device__ __forceinline__ h16x8 load8h(const _Float16* p) { h16x8 v; __builtin_memcpy(&v, p, 16); return v; }
__device__ __forceinline__ f32x4 ntload4(const float* p) {
    return __builtin_nontemporal_load((const f32x4*)p);
}

__device__ __forceinline__ void pos_to_cell(float px, float py, float pz,
                                            int& ibase, float* wxs, float* wys, float* wzs) {
    px = fminf(fmaxf(px, 0.0f), 126.9999f);
    py = fminf(fmaxf(py, 0.0f), 126.9999f);
    pz = fminf(fmaxf(pz, 0.0f), 126.9999f);
    int ix = (int)px, iy = (int)py, iz = (int)pz;
    float wx = px - (float)ix, wy = py - (float)iy, wz = pz - (float)iz;
    ibase = (ix << 14) + (iy << 7) + iz;
    wxs[0] = 1.0f - wx; wxs[1] = wx;
    wys[0] = 1.0f - wy; wys[1] = wy;
    wzs[0] = 1.0f - wz; wzs[1] = wz;
}

// opacity trilerp on the ORIGINAL f32 array; z-adjacent corners via dwordx2.
__device__ __forceinline__ float eval_op(float px, float py, float pz,
                                         const float* __restrict__ opa) {
    int ibase; float wxs[2], wys[2], wzs[2];
    pos_to_cell(px, py, pz, ibase, wxs, wys, wzs);
    float op = 0.0f;
    #pragma unroll
    for (int cx = 0; cx < 2; ++cx)
    #pragma unroll
    for (int cy = 0; cy < 2; ++cy) {
        int idx = ibase + (cx << 14) + (cy << 7);
        f32x2 pr = load2(opa + idx);
        float wxy = wxs[cx] * wys[cy];
        op = fmaf(wxy * wzs[0], pr.x, op);
        op = fmaf(wxy * wzs[1], pr.y, op);
    }
    return fminf(fmaxf(op, 0.0f), 100000.0f);
}

// ---- f32 fallback color (used if ws too small) ----
__device__ __forceinline__ void eval_color_f(float px, float py, float pz,
                                             const float* __restrict__ grid,
                                             const SH9& sh,
                                             float& cr, float& cg, float& cb) {
    int ibase; float wxs[2], wys[2], wzs[2];
    pos_to_cell(px, py, pz, ibase, wxs, wys, wzs);
    float r = 0.0f, g = 0.0f, b = 0.0f;
    #pragma unroll
    for (int cx = 0; cx < 2; ++cx)
    #pragma unroll
    for (int cy = 0; cy < 2; ++cy)
    #pragma unroll
    for (int cz = 0; cz < 2; ++cz) {
        int idx = ibase + (cx << 14) + (cy << 7) + cz;
        float wc = wxs[cx] * wys[cy] * wzs[cz];
        const float* cp = grid + (size_t)idx * 27;
        f32x4 v0 = load4(cp);
        f32x4 v1 = load4(cp + 4);
        f32x4 v2 = load4(cp + 8);
        f32x4 v3 = load4(cp + 12);
        f32x4 v4 = load4(cp + 16);
        f32x4 v5 = load4(cp + 20);
        f32x4 v6 = load4(cp + 23);
        float c0 = sh.a*v0.x + sh.b*v0.y + sh.c*v0.z + sh.d*v0.w
                 + sh.e*v1.x + sh.f*v1.y + sh.g*v1.z + sh.h*v1.w + sh.i*v2.x;
        float c1 = sh.a*v2.y + sh.b*v2.z + sh.c*v2.w + sh.d*v3.x
                 + sh.e*v3.y + sh.f*v3.z + sh.g*v3.w + sh.h*v4.x + sh.i*v4.y;
        float c2 = sh.a*v4.z + sh.b*v4.w + sh.c*v5.x + sh.d*v5.y
                 + sh.e*v5.z + sh.f*v5.w + sh.g*v6.y + sh.h*v6.z + sh.i*v6.w;
        r = fmaf(wc, c0, r);
        g = fmaf(wc, c1, g);
        b = fmaf(wc, c2, b);
    }
    cr = fminf(fmaxf(r + 0.5f, 0.0f), 100000.0f);
    cg = fminf(fmaxf(g + 0.5f, 0.0f), 100000.0f);
    cb = fminf(fmaxf(b + 0.5f, 0.0f), 100000.0f);
}

__device__ __forceinline__ float wave_incl_scan(float v, int lane) {
    #pragma unroll
    for (int off = 1; off < 64; off <<= 1) {
        float n = __shfl_up(v, (unsigned)off, 64);
        if (lane >= off) v += n;
    }
    return v;
}

__device__ __forceinline__ SH9 make_sh(float ddx, float ddy, float ddz) {
    SH9 sh;
    sh.a = 0.28209479177387814f;
    sh.b = -0.4886025119029199f * ddy;
    sh.c =  0.4886025119029199f * ddz;
    sh.d = -0.4886025119029199f * ddx;
    sh.e =  1.0925484305920792f * ddx * ddy;
    sh.f = -1.0925484305920792f * ddy * ddz;
    sh.g =  0.31539156525252005f * (2.0f*ddz*ddz - ddx*ddx - ddy*ddy);
    sh.h = -1.0925484305920792f * ddx * ddz;
    sh.i =  0.5462742152960396f * (ddx*ddx - ddy*ddy);
    return sh;
}

// pack chunk o: output 16-B chunk <-> input floats [(o>>2)*27 + (o&3)*8, +8)
__device__ __forceinline__ void pack_one(const float* __restrict__ grid,
                                         _Float16* __restrict__ pack, int o) {
    int cell = o >> 2;
    int q = o & 3;
    int base = cell * 27;
    int offa = base + ((q == 3) ? 23 : q * 8);
    int offb = (q == 3) ? offa : offa + 4;
    f32x4 a = ntload4(grid + offa);
    f32x4 b = ntload4(grid + offb);
    h16x8 out;
    if (q == 3) {
        out[0] = (_Float16)a.y; out[1] = (_Float16)a.z; out[2] = (_Float16)a.w;
        out[3] = (_Float16)0.f; out[4] = (_Float16)0.f; out[5] = (_Float16)0.f;
        out[6] = (_Float16)0.f; out[7] = (_Float16)0.f;
    } else {
        out[0] = (_Float16)a.x; out[1] = (_Float16)a.y; out[2] = (_Float16)a.z; out[3] = (_Float16)a.w;
        out[4] = (_Float16)b.x; out[5] = (_Float16)b.y; out[6] = (_Float16)b.z; out[7] = (_Float16)b.w;
    }
    __builtin_memcpy(pack + ((size_t)o << 3), &out, 16);
}

// ---- kernel 1: pure fp16 pack (HBM stream, ~360 MB) ----
__global__ __launch_bounds__(256) void pack_kernel(
    const float* __restrict__ grid, _Float16* __restrict__ pack)
{
    const int tid = blockIdx.x * 256 + threadIdx.x;
    #pragma unroll 1
    for (int i = 0; i < PACK_ITERS; i += 8) {
        #pragma unroll
        for (int j = 0; j < 8; ++j)
            pack_one(grid, pack, tid + (i + j) * PACK_THREADS);
    }
}

// ---- kernel 2: fused op/scan/color, wave per ray, lane = sample.
// op phase: lane s gathers opacity, wave-scan -> w0/w1 in-register (no wbuf).
// color phase: QUAD-cooperative gather on packed fp16 cells (round-2 layout).
__global__ __launch_bounds__(256) void fused_color_kernel(
    const float* __restrict__ x, const float* __restrict__ d,
    const float* __restrict__ tmin, const float* __restrict__ tmax,
    const float* __restrict__ opa, const _Float16* __restrict__ pack,
    float* __restrict__ out, int nrays)
{
    int gtid = blockIdx.x * blockDim.x + threadIdx.x;
    int ray = __builtin_amdgcn_readfirstlane(gtid >> 6);
    int lane = threadIdx.x & 63;
    if (ray >= nrays) return;
    int qd  = lane >> 2;    // quad id: sample-within-pass
    int sub = lane & 3;     // 16-B quarter within cell line

    float ox = x[3*ray+0], oy = x[3*ray+1], oz = x[3*ray+2];
    float ddx = d[3*ray+0], ddy = d[3*ray+1], ddz = d[3*ray+2];
    float t0 = tmin[ray];
    float range = tmax[ray] - t0;
    float delta = range * 0.0078125f;
    SH9 sh = make_sh(ddx, ddy, ddz);

    // ---- op phase, chunk 0: samples 0..63 ----
    float tt = range * (0.05f + (float)lane * 0.0078125f) + t0;
    {
    }
    float px0 = ox + tt*ddx, py0 = oy + tt*ddy, pz0 = oz + tt*ddz;
    float opv = eval_op(px0, py0, pz0, opa);
    float dts = -delta * opv;
    float incl = wave_incl_scan(dts, lane);
    float cum = incl - dts;
    float total0 = __shfl(incl, 63, 64);
    float w0 = __expf(cum) * (1.0f - __expf(dts));

    // ---- op phase, chunk 1: samples 64..114 ----
    float w1 = 0.0f;
    if (total0 > LOG_TSKIP) {
        int s1 = 64 + lane;
        float dts1 = 0.0f;
        if (s1 < NS) {
            float t1s = range * (0.05f + (float)s1 * 0.0078125f) + t0;
            float qx = ox + t1s*ddx, qy = oy + t1s*ddy, qz = oz + t1s*ddz;
            dts1 = -delta * eval_op(qx, qy, qz, opa);
        }
        float incl1 = wave_incl_scan(dts1, lane);
        float cum1 = total0 + incl1 - dts1;
        w1 = __expf(cum1) * (1.0f - __expf(dts1));   // ==0 for s1>=NS
    }

    // ---- color phase ----
    // per-lane dual masked SH vectors:
    // sub0: ch0-7  = R sh0-7          -> s0={a..h}, s1=0
    // sub1: ch8-15 = R sh8, G sh0-6   -> s0={i,0..}, s1={0,a..g}
    // sub2: ch16-23= G sh7-8, B sh0-5 -> s0={h,i,0..}, s1={0,0,a..f}
    // sub3: ch24-26= B sh6-8 (+pad0)  -> s0={g,h,i,0..}, s1=0
    float s00,s01,s02,s03,s04,s05,s06,s07;
    float s10,s11,s12,s13,s14,s15,s16,s17;
    if (sub == 0) {
        s00=sh.a;s01=sh.b;s02=sh.c;s03=sh.d;s04=sh.e;s05=sh.f;s06=sh.g;s07=sh.h;
        s10=0.f;s11=0.f;s12=0.f;s13=0.f;s14=0.f;s15=0.f;s16=0.f;s17=0.f;
    } else if (sub == 1) {
        s00=sh.i;s01=0.f;s02=0.f;s03=0.f;s04=0.f;s05=0.f;s06=0.f;s07=0.f;
        s10=0.f;s11=sh.a;s12=sh.b;s13=sh.c;s14=sh.d;s15=sh.e;s16=sh.f;s17=sh.g;
    } else if (sub == 2) {
        s00=sh.h;s01=sh.i;s02=0.f;s03=0.f;s04=0.f;s05=0.f;s06=0.f;s07=0.f;
        s10=0.f;s11=0.f;s12=sh.a;s13=sh.b;s14=sh.c;s15=sh.d;s16=sh.e;s17=sh.f;
    } else {
        s00=sh.g;s01=sh.h;s02=sh.i;s03=0.f;s04=0.f;s05=0.f;s06=0.f;s07=0.f;
        s10=0.f;s11=0.f;s12=0.f;s13=0.f;s14=0.f;s15=0.f;s16=0.f;s17=0.f;
    }

    unsigned long long b0 = __ballot(w0 > WEPS);
    unsigned long long b1 = __ballot(w1 > WEPS);

    float accR = 0.0f, accG = 0.0f, accB = 0.0f;

    #pragma unroll 1
    for (int p = 0; p < 8; ++p) {
        unsigned long long bsel = (p < 4) ? b0 : b1;
        int shl = (p & 3) << 4;
        if (((bsel >> shl) & 0xFFFFull) == 0) continue;   // whole pass dead
        int s = (p << 4) + qd;                            // sample index
        float ws = __shfl((p < 4) ? w0 : w1, s & 63, 64); // quad-uniform
        if (ws > WEPS) {
            float st = range * (0.05f + (float)s * 0.0078125f) + t0;
            float px = ox + st*ddx, py = oy + st*ddy, pz = oz + st*ddz;
            int ibase; float wxs[2], wys[2], wzs[2];
            pos_to_cell(px, py, pz, ibase, wxs, wys, wzs);
            float d0a = 0.0f, d1a = 0.0f;   // wc-weighted dual dots over corners
            #pragma unroll
            for (int cx = 0; cx < 2; ++cx)
            #pragma unroll
            for (int cy = 0; cy < 2; ++cy)
            #pragma unroll
            for (int cz = 0; cz < 2; ++cz) {
                int idx = ibase + (cx << 14) + (cy << 7) + cz;
                float wc = wxs[cx] * wys[cy] * wzs[cz];
                const _Float16* cp = pack + ((size_t)idx << 5) + (sub << 3);
                h16x8 v = load8h(cp);
                float f0=(float)v[0], f1=(float)v[1], f2=(float)v[2], f3=(float)v[3];
                float f4=(float)v[4], f5=(float)v[5], f6=(float)v[6], f7=(float)v[7];
                float e0 = s00*f0 + s01*f1 + s02*f2 + s03*f3
                         + s04*f4 + s05*f5 + s06*f6 + s07*f7;
                float e1 = s10*f0 + s11*f1 + s12*f2 + s13*f3
                         + s14*f4 + s15*f5 + s16*f6 + s17*f7;
                d0a = fmaf(wc, e0, d0a);
                d1a = fmaf(wc, e1, d1a);
            }
            // route dual dots to colors (per-sub mapping)
            float rp = (sub < 2)  ? d0a : 0.0f;
            float gp = (sub == 1) ? d1a : ((sub == 2) ? d0a : 0.0f);
            float bp = (sub == 2) ? d1a : ((sub == 3) ? d0a : 0.0f);
            // quad reduce (all 4 quad-lanes active together)
            rp += __shfl_xor(rp, 1, 64); rp += __shfl_xor(rp, 2, 64);
            gp += __shfl_xor(gp, 1, 64); gp += __shfl_xor(gp, 2, 64);
            bp += __shfl_xor(bp, 1, 64); bp += __shfl_xor(bp, 2, 64);
            float cr = fminf(fmaxf(rp + 0.5f, 0.0f), 100000.0f);
            float cg = fminf(fmaxf(gp + 0.5f, 0.0f), 100000.0f);
            float cb = fminf(fmaxf(bp + 0.5f, 0.0f), 100000.0f);
            accR = fmaf(ws, cr, accR);
            accG = fmaf(ws, cg, accG);
            accB = fmaf(ws, cb, accB);
        }
    }

    // quad lanes hold identical acc -> reduce across quads only
    #pragma unroll
    for (int off = 4; off < 64; off <<= 1) {
        accR += __shfl_xor(accR, off, 64);
        accG += __shfl_xor(accG, off, 64);
        accB += __shfl_xor(accB, off, 64);
    }
    if (lane == 0) {
        out[3*ray+0] = accR;
        out[3*ray+1] = accG;
        out[3*ray+2] = accB;
    }
}

// ---- fallback: fully-fused f32 path (ws too small) ----
__global__ __launch_bounds__(256) void rf_fallback(
    const float* __restrict__ x, const float* __restrict__ d,
    const float* __restrict__ tmin, const float* __restrict__ tmax,
    const float* __restrict__ grid, const float* __restrict__ opa,
    float* __restrict__ out, int nrays)
{
    int gtid = blockIdx.x * blockDim.x + threadIdx.x;
    int ray = __builtin_amdgcn_readfirstlane(gtid >> 6);
    int lane = threadIdx.x & 63;
    if (ray >= nrays) return;

    float ox = x[3*ray+0], oy = x[3*ray+1], oz = x[3*ray+2];
    float ddx = d[3*ray+0], ddy = d[3*ray+1], ddz = d[3*ray+2];
    float t0 = tmin[ray], t1 = tmax[ray];
    float range = t1 - t0;
    float delta = range * 0.0078125f;
    SH9 sh = make_sh(ddx, ddy, ddz);

    float accR = 0.0f, accG = 0.0f, accB = 0.0f;
    {
        float tt = range * (0.05f + (float)lane * 0.0078125f) + t0;
        float px = ox + tt*ddx, py = oy + tt*ddy, pz = oz + tt*ddz;
        float opv = eval_op(px, py, pz, opa);
        float dts = -delta * opv;
        float incl = wave_incl_scan(dts, lane);
        float cum = incl - dts;
        float total0 = __shfl(incl, 63, 64);
        float w = __expf(cum) * (1.0f - __expf(dts));
        if (w > WEPS) {
            float cr, cg, cb;
            eval_color_f(px, py, pz, grid, sh, cr, cg, cb);
            accR = w * cr; accG = w * cg; accB = w * cb;
        }
        if (total0 > LOG_TSKIP) {
            int s1 = 64 + lane;
            float dts1 = 0.0f;
            float px1 = 0.f, py1 = 0.f, pz1 = 0.f;
            if (s1 < NS) {
                float t1s = range * (0.05f + (float)s1 * 0.0078125f) + t0;
                px1 = ox + t1s*ddx; py1 = oy + t1s*ddy; pz1 = oz + t1s*ddz;
                dts1 = -delta * eval_op(px1, py1, pz1, opa);
            }
            float incl1 = wave_incl_scan(dts1, lane);
            float cum1 = total0 + incl1 - dts1;
            float w1 = __expf(cum1) * (1.0f - __expf(dts1));
            if (w1 > WEPS) {
                float cr, cg, cb;
                eval_color_f(px1, py1, pz1, grid, sh, cr, cg, cb);
                accR = fmaf(w1, cr, accR);
                accG = fmaf(w1, cg, accG);
                accB = fmaf(w1, cb, accB);
            }
        }
    }
    #pragma unroll
    for (int off = 32; off > 0; off >>= 1) {
        accR += __shfl_xor(accR, off, 64);
        accG += __shfl_xor(accG, off, 64);
        accB += __shfl_xor(accB, off, 64);
    }
    if (lane == 0) {
        out[3*ray+0] = accR;
        out[3*ray+1] = accG;
        out[3*ray+2] = accB;
    }
}

extern "C" void kernel_launch(void* const* d_in, const int* in_sizes, int n_in,
                              void* d_out, int out_size, void* d_ws, size_t ws_size,
                              hipStream_t stream) {
    const float* x    = (const float*)d_in[0];
    const float* d    = (const float*)d_in[1];
    const float* tmin = (const float*)d_in[2];
    const float* tmax = (const float*)d_in[3];
    const float* grid = (const float*)d_in[4];
    const float* opa  = (const float*)d_in[5];
    float* out = (float*)d_out;

    int nrays = in_sizes[0] / 3;                 // 32768
    int blocks = (nrays * 64 + 255) / 256;       // 8192

    if (ws_size >= NEED_BYTES) {
        _Float16* pack = (_Float16*)d_ws;
        pack_kernel<<<PACK_BLOCKS, 256, 0, stream>>>(grid, pack);
        fused_color_kernel<<<blocks, 256, 0, stream>>>(x, d, tmin, tmax, opa, pack, out, nrays);
    } else {
        rf_fallback<<<blocks, 256, 0, stream>>>(x, d, tmin, tmax, grid, opa, out, nrays);
    }
}

// Round 4
// 390.125 us; speedup vs baseline: 1.0806x; 1.0041x over previous
//
#include <hip/hip_runtime.h>

#define NS 115              // contributing samples (S=116, last one unused)
#define WEPS 5e-5f          // per-sample color skip
#define LOG_TSKIP -6.9078f  // chunk1 skip when T < 1e-3

typedef float f32x4 __attribute__((ext_vector_type(4)));
typedef float f32x2 __attribute__((ext_vector_type(2)));

struct SH9 { float a,b,c,d,e,f,g,h,i; };

__device__ __forceinline__ f32x4 load4(const float* p) { f32x4 v; __builtin_memcpy(&v, p, 16); return v; }
__device__ __forceinline__ f32x2 load2(const float* p) { f32x2 v; __builtin_memcpy(&v, p, 8);  return v; }

__device__ __forceinline__ void pos_to_cell(float px, float py, float pz,
                                            int& ibase, float* wxs, float* wys, float* wzs) {
    px = fminf(fmaxf(px, 0.0f), 126.9999f);
    py = fminf(fmaxf(py, 0.0f), 126.9999f);
    pz = fminf(fmaxf(pz, 0.0f), 126.9999f);
    int ix = (int)px, iy = (int)py, iz = (int)pz;
    float wx = px - (float)ix, wy = py - (float)iy, wz = pz - (float)iz;
    ibase = (ix << 14) + (iy << 7) + iz;
    wxs[0] = 1.0f - wx; wxs[1] = wx;
    wys[0] = 1.0f - wy; wys[1] = wy;
    wzs[0] = 1.0f - wz; wzs[1] = wz;
}

// opacity trilerp; z-adjacent corners via dwordx2.
__device__ __forceinline__ float eval_op(float px, float py, float pz,
                                         const float* __restrict__ opa) {
    int ibase; float wxs[2], wys[2], wzs[2];
    pos_to_cell(px, py, pz, ibase, wxs, wys, wzs);
    float op = 0.0f;
    #pragma unroll
    for (int cx = 0; cx < 2; ++cx)
    #pragma unroll
    for (int cy = 0; cy < 2; ++cy) {
        int idx = ibase + (cx << 14) + (cy << 7);
        f32x2 pr = load2(opa + idx);
        float wxy = wxs[cx] * wys[cy];
        op = fmaf(wxy * wzs[0], pr.x, op);
        op = fmaf(wxy * wzs[1], pr.y, op);
    }
    return fminf(fmaxf(op, 0.0f), 100000.0f);
}

__device__ __forceinline__ float wave_incl_scan(float v, int lane) {
    #pragma unroll
    for (int off = 1; off < 64; off <<= 1) {
        float n = __shfl_up(v, (unsigned)off, 64);
        if (lane >= off) v += n;
    }
    return v;
}

__device__ __forceinline__ SH9 make_sh(float ddx, float ddy, float ddz) {
    SH9 sh;
    sh.a = 0.28209479177387814f;
    sh.b = -0.4886025119029199f * ddy;
    sh.c =  0.4886025119029199f * ddz;
    sh.d = -0.4886025119029199f * ddx;
    sh.e =  1.0925484305920792f * ddx * ddy;
    sh.f = -1.0925484305920792f * ddy * ddz;
    sh.g =  0.31539156525252005f * (2.0f*ddz*ddz - ddx*ddx - ddy*ddy);
    sh.h = -1.0925484305920792f * ddx * ddz;
    sh.i =  0.5462742152960396f * (ddx*ddx - ddy*ddy);
    return sh;
}

// ---- single fused kernel: op/scan + color, wave per ray, lane = sample.
// op phase: lane s gathers opacity, wave-scan -> w0/w1 in-register.
// color phase: QUAD-cooperative gather DIRECTLY on the f32 grid (no pack):
//   sub k covers channels [8k, 8k+8) of the 27-float cell; sub3 loads at
//   cp+23 (floats 23..26) with a shifted mask {0,g,h,i,...} so ch23 isn't
//   double-counted and we never read past the last cell.
__global__ __launch_bounds__(256) void fused_color_kernel(
    const float* __restrict__ x, const float* __restrict__ d,
    const float* __restrict__ tmin, const float* __restrict__ tmax,
    const float* __restrict__ opa, const float* __restrict__ grid,
    float* __restrict__ out, int nrays)
{
    int gtid = blockIdx.x * blockDim.x + threadIdx.x;
    int ray = __builtin_amdgcn_readfirstlane(gtid >> 6);
    int lane = threadIdx.x & 63;
    if (ray >= nrays) return;
    int qd  = lane >> 2;    // quad id: sample-within-pass
    int sub = lane & 3;     // channel-range within cell

    float ox = x[3*ray+0], oy = x[3*ray+1], oz = x[3*ray+2];
    float ddx = d[3*ray+0], ddy = d[3*ray+1], ddz = d[3*ray+2];
    float t0 = tmin[ray];
    float range = tmax[ray] - t0;
    float delta = range * 0.0078125f;
    SH9 sh = make_sh(ddx, ddy, ddz);

    // ---- op phase, chunk 0: samples 0..63 ----
    float tt = range * (0.05f + (float)lane * 0.0078125f) + t0;
    float px0 = ox + tt*ddx, py0 = oy + tt*ddy, pz0 = oz + tt*ddz;
    float opv = eval_op(px0, py0, pz0, opa);
    float dts = -delta * opv;
    float incl = wave_incl_scan(dts, lane);
    float cum = incl - dts;
    float total0 = __shfl(incl, 63, 64);
    float w0 = __expf(cum) * (1.0f - __expf(dts));

    // ---- op phase, chunk 1: samples 64..114 ----
    float w1 = 0.0f;
    if (total0 > LOG_TSKIP) {
        int s1 = 64 + lane;
        float dts1 = 0.0f;
        if (s1 < NS) {
            float t1s = range * (0.05f + (float)s1 * 0.0078125f) + t0;
            float qx = ox + t1s*ddx, qy = oy + t1s*ddy, qz = oz + t1s*ddz;
            dts1 = -delta * eval_op(qx, qy, qz, opa);
        }
        float incl1 = wave_incl_scan(dts1, lane);
        float cum1 = total0 + incl1 - dts1;
        w1 = __expf(cum1) * (1.0f - __expf(dts1));   // ==0 for s1>=NS
    }

    // ---- color phase: per-lane dual masked SH vectors ----
    // sub0: ch0-7  = R sh0-7          -> s0={a..h}, s1=0
    // sub1: ch8-15 = R sh8, G sh0-6   -> s0={i,0..}, s1={0,a..g}
    // sub2: ch16-23= G sh7-8, B sh0-5 -> s0={h,i,0..}, s1={0,0,a..f}
    // sub3: loads f23..f26; ch24-26 = B sh6-8 -> s0={0,g,h,i,0..}, s1=0
    float s00,s01,s02,s03,s04,s05,s06,s07;
    float s10,s11,s12,s13,s14,s15,s16,s17;
    if (sub == 0) {
        s00=sh.a;s01=sh.b;s02=sh.c;s03=sh.d;s04=sh.e;s05=sh.f;s06=sh.g;s07=sh.h;
        s10=0.f;s11=0.f;s12=0.f;s13=0.f;s14=0.f;s15=0.f;s16=0.f;s17=0.f;
    } else if (sub == 1) {
        s00=sh.i;s01=0.f;s02=0.f;s03=0.f;s04=0.f;s05=0.f;s06=0.f;s07=0.f;
        s10=0.f;s11=sh.a;s12=sh.b;s13=sh.c;s14=sh.d;s15=sh.e;s16=sh.f;s17=sh.g;
    } else if (sub == 2) {
        s00=sh.h;s01=sh.i;s02=0.f;s03=0.f;s04=0.f;s05=0.f;s06=0.f;s07=0.f;
        s10=0.f;s11=0.f;s12=sh.a;s13=sh.b;s14=sh.c;s15=sh.d;s16=sh.e;s17=sh.f;
    } else {
        s00=0.f;s01=sh.g;s02=sh.h;s03=sh.i;s04=0.f;s05=0.f;s06=0.f;s07=0.f;
        s10=0.f;s11=0.f;s12=0.f;s13=0.f;s14=0.f;s15=0.f;s16=0.f;s17=0.f;
    }
    // per-lane byte offsets within the cell
    int offa = (sub == 3) ? 23 : (sub << 3);
    int offb = (sub == 3) ? 23 : offa + 4;

    unsigned long long b0 = __ballot(w0 > WEPS);
    unsigned long long b1 = __ballot(w1 > WEPS);

    float accR = 0.0f, accG = 0.0f, accB = 0.0f;

    #pragma unroll 1
    for (int p = 0; p < 8; ++p) {
        unsigned long long bsel = (p < 4) ? b0 : b1;
        int shl = (p & 3) << 4;
        if (((bsel >> shl) & 0xFFFFull) == 0) continue;   // whole pass dead
        int s = (p << 4) + qd;                            // sample index
        float ws = __shfl((p < 4) ? w0 : w1, s & 63, 64); // quad-uniform
        if (ws > WEPS) {
            float st = range * (0.05f + (float)s * 0.0078125f) + t0;
            float px = ox + st*ddx, py = oy + st*ddy, pz = oz + st*ddz;
            int ibase; float wxs[2], wys[2], wzs[2];
            pos_to_cell(px, py, pz, ibase, wxs, wys, wzs);
            float d0a = 0.0f, d1a = 0.0f;   // wc-weighted dual dots over corners
            #pragma unroll
            for (int cx = 0; cx < 2; ++cx)
            #pragma unroll
            for (int cy = 0; cy < 2; ++cy)
            #pragma unroll
            for (int cz = 0; cz < 2; ++cz) {
                int idx = ibase + (cx << 14) + (cy << 7) + cz;
                float wc = wxs[cx] * wys[cy] * wzs[cz];
                const float* cp = grid + (size_t)idx * 27;
                f32x4 va = load4(cp + offa);
                f32x4 vb = load4(cp + offb);
                float f0=va.x, f1=va.y, f2=va.z, f3=va.w;
                float f4=vb.x, f5=vb.y, f6=vb.z, f7=vb.w;
                float e0 = s00*f0 + s01*f1 + s02*f2 + s03*f3
                         + s04*f4 + s05*f5 + s06*f6 + s07*f7;
                float e1 = s10*f0 + s11*f1 + s12*f2 + s13*f3
                         + s14*f4 + s15*f5 + s16*f6 + s17*f7;
                d0a = fmaf(wc, e0, d0a);
                d1a = fmaf(wc, e1, d1a);
            }
            // route dual dots to colors (per-sub mapping)
            float rp = (sub < 2)  ? d0a : 0.0f;
            float gp = (sub == 1) ? d1a : ((sub == 2) ? d0a : 0.0f);
            float bp = (sub == 2) ? d1a : ((sub == 3) ? d0a : 0.0f);
            // quad reduce (all 4 quad-lanes active together)
            rp += __shfl_xor(rp, 1, 64); rp += __shfl_xor(rp, 2, 64);
            gp += __shfl_xor(gp, 1, 64); gp += __shfl_xor(gp, 2, 64);
            bp += __shfl_xor(bp, 1, 64); bp += __shfl_xor(bp, 2, 64);
            float cr = fminf(fmaxf(rp + 0.5f, 0.0f), 100000.0f);
            float cg = fminf(fmaxf(gp + 0.5f, 0.0f), 100000.0f);
            float cb = fminf(fmaxf(bp + 0.5f, 0.0f), 100000.0f);
            accR = fmaf(ws, cr, accR);
            accG = fmaf(ws, cg, accG);
            accB = fmaf(ws, cb, accB);
        }
    }

    // quad lanes hold identical acc -> reduce across quads only
    #pragma unroll
    for (int off = 4; off < 64; off <<= 1) {
        accR += __shfl_xor(accR, off, 64);
        accG += __shfl_xor(accG, off, 64);
        accB += __shfl_xor(accB, off, 64);
    }
    if (lane == 0) {
        out[3*ray+0] = accR;
        out[3*ray+1] = accG;
        out[3*ray+2] = accB;
    }
}

extern "C" void kernel_launch(void* const* d_in, const int* in_sizes, int n_in,
                              void* d_out, int out_size, void* d_ws, size_t ws_size,
                              hipStream_t stream) {
    const float* x    = (const float*)d_in[0];
    const float* d    = (const float*)d_in[1];
    const float* tmin = (const float*)d_in[2];
    const float* tmax = (const float*)d_in[3];
    const float* grid = (const float*)d_in[4];
    const float* opa  = (const float*)d_in[5];
    float* out = (float*)d_out;

    int nrays = in_sizes[0] / 3;                 // 32768
    int blocks = (nrays * 64 + 255) / 256;       // 8192

    (void)d_ws; (void)ws_size;
    fused_color_kernel<<<blocks, 256, 0, stream>>>(x, d, tmin, tmax, opa, grid, out, nrays);
}